// Round 2
// 732.634 us; speedup vs baseline: 1.1864x; 1.1864x over previous
//
#include <hip/hip_runtime.h>
#include <stdint.h>

typedef unsigned long long u64;
typedef uint32_t u32;
typedef uint16_t u16;

// Net: x (8192,6,32,48)
// L1: (6,32,48)->(12,15,23)   L2: (12,15,23)->(24,7,11)
// L3: (24,7,11)->(48,3,5)     L4: (48,3,5)->(96,1,2)
// Linear: 192 -> 360
#define NIMG 8192

// ---------------- workspace layout (bytes) ----------------
static const size_t O_TOT = 0;                               // 512 u64 stats (zeroed by pack_w_k)
static const size_t O_W1  = 4096;                            // 120 u64
static const size_t O_W2  = O_W1 + 120*8;                    // 240 u64
static const size_t O_W3  = O_W2 + 240*8;                    // 960 u64
static const size_t O_W4  = O_W3 + 960*8;                    // 3840 u64
static const size_t O_WL  = O_W4 + 3840*8;                   // 2160 u64
static const size_t O_SA  = 65536;                           // S1 (u32x3/px, 33.9MB), later S3 (48 sh/px, 11.8MB)
static const size_t O_SB  = O_SA + (size_t)NIMG*345*12;      // S2 (24 sh/px, 30.3MB), later S4 (96 sh/px, 3.1MB)

// ---------------- weight packing + stats zeroing (unchanged layout) ----------------
__global__ void pack_w_k(const float* w1, const float* w2, const float* w3,
                         const float* w4, const float* wl,
                         u64* W1, u64* W2, u64* W3, u64* W4, u64* WL, u64* tot) {
  if (blockIdx.x == 5) {              // zero the stats accumulators (ws is poisoned 0xAA)
    int t = threadIdx.x;
    tot[t] = 0; tot[t+256] = 0;
    return;
  }
  int u = blockIdx.x*256 + threadIdx.x;
  if (u < 60) {                       // L1: unit=(co*5+kh); 30-bit planes, ternary combined
    int co = u/5, kh = u%5;
    u64 wp=0, wn=0;
    for (int kw=0; kw<5; kw++) for (int ci=0; ci<6; ci++) {
      float v = w1[co*150 + ci*25 + kh*5 + kw];
      int pos = 6*kw + ci;
      if (v > 0.f) wp |= 1ull<<pos; else if (v < 0.f) wn |= 1ull<<pos;
    }
    W1[u*2]   = wp | (wn<<32);        // counts +1 products vs X = xp | xn<<32
    W1[u*2+1] = wn | (wp<<32);        // (kept for layout compat; convs now use word0 only)
  } else if (u < 180) {               // L2: 60-bit single plane
    int t = u-60; int co=t/5, kh=t%5;
    u64 wp=0, wn=0;
    for (int kw=0; kw<5; kw++) for (int ci=0; ci<12; ci++) {
      float v = w2[co*300 + ci*25 + kh*5 + kw];
      int pos = 12*kw+ci;
      if (v>0.f) wp |= 1ull<<pos; else if (v<0.f) wn |= 1ull<<pos;
    }
    W2[t*2] = wp; W2[t*2+1] = wn;
  } else if (u < 420) {               // L3: 120-bit, 2 words per plane
    int t = u-180; int co=t/5, kh=t%5;
    u64 wp[2]={0,0}, wn[2]={0,0};
    for (int kw=0; kw<5; kw++) for (int ci=0; ci<24; ci++) {
      float v = w3[co*600 + ci*25 + kh*5 + kw];
      int pos = 24*kw+ci;
      if (v>0.f) wp[pos>>6] |= 1ull<<(pos&63); else if (v<0.f) wn[pos>>6] |= 1ull<<(pos&63);
    }
    W3[t*4]=wp[0]; W3[t*4+1]=wp[1]; W3[t*4+2]=wn[0]; W3[t*4+3]=wn[1];
  } else if (u < 900) {               // L4: 240-bit, 4 words per plane
    int t = u-420; int co=t/5, kh=t%5;
    u64 wp[4]={0,0,0,0}, wn[4]={0,0,0,0};
    for (int kw=0; kw<5; kw++) for (int ci=0; ci<48; ci++) {
      float v = w4[co*1200 + ci*25 + kh*5 + kw];
      int pos = 48*kw+ci;
      if (v>0.f) wp[pos>>6] |= 1ull<<(pos&63); else if (v<0.f) wn[pos>>6] |= 1ull<<(pos&63);
    }
    for (int j=0;j<4;j++){ W4[t*8+j]=wp[j]; W4[t*8+4+j]=wn[j]; }
  } else if (u < 1260) {              // linear: 192-bit, 3 words per plane
    int o = u-900;
    u64 wp[3]={0,0,0}, wn[3]={0,0,0};
    for (int k=0;k<192;k++){
      float v = wl[o*192+k];
      if (v>0.f) wp[k>>6] |= 1ull<<(k&63); else if (v<0.f) wn[k>>6] |= 1ull<<(k&63);
    }
    for (int j=0;j<3;j++){ WL[o*6+j]=wp[j]; WL[o*6+3+j]=wn[j]; }
  }
}

// ---------------- BN param computation (identical math to previous version) ----------------
template<int C>
__device__ inline void bn_params(const u64* tot, const float* g, const float* be, double cnt,
                                 float* s_mu, float* s_k, float* s_be) {
  int t = threadIdx.x;
  if (t < C) {
    long long sum = (long long)tot[t*2];
    long long sq  = (long long)tot[t*2+1];
    double mu  = (double)sum / cnt;
    double var = (double)sq / cnt - mu*mu;
    double kk  = (double)g[t] / sqrt(var + 1e-5);
    s_mu[t] = (float)mu; s_k[t] = (float)kk; s_be[t] = be[t];
  }
  __syncthreads();
}

// ---------------- block stats reduction ----------------
// 256-thread block = FOUR 64-lane waves (wid 0..3). Each thread holds NV ints
// (C sums then C sq for its lane-group = lane % LANES; group g owns channels
// [g*C, g*C+C)). Shuffle-reduce within wave down to lanes [0,LANES), stage the
// 4 wave partials in LDS (rl: LANES*NV*4 ints), final atomics by threads < LANES*NV.
template<int NV, int LANES, int C>
__device__ inline void block_stats(int (&v)[NV], u64* tot, int* rl) {
  #pragma unroll
  for (int o = 32; o >= LANES; o >>= 1)
    #pragma unroll
    for (int r = 0; r < NV; r++) v[r] += __shfl_down(v[r], o, 64);
  int lane = threadIdx.x & 63, wid = threadIdx.x >> 6;   // 4 waves per block
  if (lane < LANES) {
    #pragma unroll
    for (int r = 0; r < NV; r++) rl[(lane*NV + r)*4 + wid] = v[r];
  }
  __syncthreads();
  int t = threadIdx.x;
  if (t < LANES*NV) {
    int g = t / NV, r = t % NV;
    int s = rl[t*4] + rl[t*4+1] + rl[t*4+2] + rl[t*4+3];
    int cc = g*C + (r < C ? r : r - C);
    atomicAdd(&tot[cc*2 + (r < C ? 0 : 1)], (u64)(long long)s);
  }
}

// ---------------- L1 fused: binarize x + conv1 + stats1 ----------------
// 2048 blocks x 4 images (two pairs). X1 ternary image staged in LDS; S1 written
// once to global (s8 x12 packed in 3 u32/px) for thresh in layer2.
// Identity: S = popcP - popcN = 2*popc(X & W+) - popc(X)   (weights never exactly 0)
__global__ __launch_bounds__(256) void layer1_k(const float* __restrict__ x,
    const u64* __restrict__ W1, u32* __restrict__ S1, u64* __restrict__ tot) {
  __shared__ u16 X1[2][32][50];
  __shared__ int rl[24*4];
  int t = threadIdx.x;
  int acc[12], sq[12];
  #pragma unroll
  for (int i=0;i<12;i++){ acc[i]=0; sq[i]=0; }
  for (int pr=0; pr<2; pr++) {
    int n0 = blockIdx.x*4 + pr*2;
    // binarize 2 images (3072 pixel positions)
    for (int u=t; u<3072; u+=256) {
      int img = (u >= 1536) ? 1 : 0;
      int q = u - img*1536;
      int h = q/48, w = q%48;
      const float* xb = x + (size_t)(n0+img)*9216 + q;
      u32 v = 0;
      #pragma unroll
      for (int c=0;c<6;c++){ float f = xb[c*1536];
        v |= (f>0.f ? 1u:0u)<<c; v |= (f<0.f ? 1u:0u)<<(8+c); }
      X1[img][h][w+1] = (u16)v;
      if (w==0)  X1[img][h][0]  = 0;
      if (w==47) X1[img][h][49] = 0;
    }
    __syncthreads();
    // conv1: 2 x 345 output pixels
    for (int u=t; u<690; u+=256) {
      int img = (u >= 345) ? 1 : 0;
      int p = u - img*345;
      int oh = p/23, ow = p%23;
      int P[12], T = 0;
      #pragma unroll
      for (int i=0;i<12;i++) P[i]=0;
      for (int kh=0; kh<5; kh++) {
        int row = 2*oh-1+kh;
        if ((unsigned)row >= 32u) continue;
        const u16* xr = &X1[img][row][2*ow];
        u64 xp=0, xn=0;
        #pragma unroll
        for (int i=0;i<5;i++){ u32 v = xr[i];
          xp |= (u64)(v & 63u) << (6*i);
          xn |= (u64)(v >> 8)  << (6*i); }
        u64 X = xp | (xn<<32);
        T += __popcll(X);
        const u64* wr = W1 + kh*2;
        #pragma unroll
        for (int co=0;co<12;co++)
          P[co] += __popcll(X & wr[co*10]);
      }
      int S[12];
      #pragma unroll
      for (int co=0;co<12;co++){ S[co] = 2*P[co] - T; acc[co]+=S[co]; sq[co]+=S[co]*S[co]; }
      u32* o = S1 + ((size_t)(n0+img)*345 + p)*3;
      #pragma unroll
      for (int j=0;j<3;j++)
        o[j] = (u32)(S[4*j]&255) | ((u32)(S[4*j+1]&255)<<8) |
               ((u32)(S[4*j+2]&255)<<16) | ((u32)(S[4*j+3]&255)<<24);
    }
    __syncthreads();
  }
  int v[24];
  #pragma unroll
  for (int c=0;c<12;c++){ v[c]=acc[c]; v[12+c]=sq[c]; }
  block_stats<24,1,12>(v, tot, rl);
}

// ---------------- L2 fused: thresh1 + conv2 + stats2 ----------------
// 1024 blocks x 8 images. A2 (15x25 u16/img) staged in LDS.
__global__ __launch_bounds__(256) void layer2_k(const u32* __restrict__ S1, u64* tot,
    const float* __restrict__ g, const float* __restrict__ be,
    const u64* __restrict__ W2, short* __restrict__ S2) {
  __shared__ float mu[12], kk[12], bb[12];
  bn_params<12>(tot, g, be, 2826240.0, mu, kk, bb);
  __shared__ u16 A2[8][15][25];
  __shared__ int rl[48*4];
  int t = threadIdx.x;
  int n0 = blockIdx.x*8;
  // thresh1: 8 x 345 px
  for (int u=t; u<8*345; u+=256) {
    int img = u/345, p = u%345;
    int oh = p/23, ow = p%23;
    const u32* s = S1 + ((size_t)(n0+img)*345 + p)*3;
    u32 w0=s[0], w1=s[1], w2v=s[2];
    u32 wv = 0;
    #pragma unroll
    for (int c=0;c<12;c++){
      u32 w = (c<4) ? w0 : (c<8) ? w1 : w2v;
      int sv = (int)(w << ((3-(c&3))*8)) >> 24;   // sign-extend s8
      float v = ((float)sv-mu[c])*kk[c]+bb[c];
      wv |= (v>0.f?1u:0u)<<c;
    }
    A2[img][oh][ow+1] = (u16)wv;
    if (ow==0)  A2[img][oh][0]  = 0;
    if (ow==22) A2[img][oh][24] = 0;
  }
  __syncthreads();
  int acc[24], sq[24];
  #pragma unroll
  for (int i=0;i<24;i++){ acc[i]=0; sq[i]=0; }
  // conv2: 8 x 77 px
  for (int u=t; u<8*77; u+=256) {
    int img = u/77, p = u%77;
    int oh = p/11, ow = p%11;
    int P[24], T = 0;
    #pragma unroll
    for (int i=0;i<24;i++) P[i]=0;
    for (int kh=0; kh<5; kh++) {
      int row = 2*oh-1+kh;
      if ((unsigned)row >= 15u) continue;
      const u16* xr = &A2[img][row][2*ow];
      u64 X = 0;
      #pragma unroll
      for (int i=0;i<5;i++) X |= (u64)xr[i] << (12*i);
      T += __popcll(X);
      const u64* wr = W2 + kh*2;
      #pragma unroll
      for (int co=0;co<24;co++)
        P[co] += __popcll(X & wr[co*10]);
    }
    short* o = S2 + ((size_t)(n0+img)*77 + p)*24;
    #pragma unroll
    for (int co=0;co<24;co++){ int sv = 2*P[co]-T; o[co]=(short)sv; acc[co]+=sv; sq[co]+=sv*sv; }
  }
  int v[48];
  #pragma unroll
  for (int c=0;c<24;c++){ v[c]=acc[c]; v[24+c]=sq[c]; }
  block_stats<48,1,24>(v, tot+24, rl);
}

// ---------------- L3 fused: thresh2 + conv3 + stats3 ----------------
// 512 blocks x 16 images. A3 (7x13 u32/img) in LDS. Channels split in 2 groups of 24;
// a thread's group = t&1 is invariant across its grid-stride iterations.
__global__ __launch_bounds__(256) void layer3_k(const short* __restrict__ S2, u64* tot,
    const float* __restrict__ g, const float* __restrict__ be,
    const u64* __restrict__ W3, short* __restrict__ S3) {
  __shared__ float mu[24], kk[24], bb[24];
  bn_params<24>(tot+24, g, be, 630784.0, mu, kk, bb);
  __shared__ u32 A3[16][7][13];
  __shared__ int rl[2*48*4];
  int t = threadIdx.x;
  int n0 = blockIdx.x*16;
  // thresh2: 16 x 77 px
  for (int u=t; u<16*77; u+=256) {
    int img = u/77, p = u%77;
    int oh = p/11, ow = p%11;
    const int4* s4 = (const int4*)(S2 + ((size_t)(n0+img)*77 + p)*24);
    int4 A=s4[0], B=s4[1], Cv=s4[2];
    int wvals[12]={A.x,A.y,A.z,A.w,B.x,B.y,B.z,B.w,Cv.x,Cv.y,Cv.z,Cv.w};
    u32 wv = 0;
    #pragma unroll
    for (int j=0;j<12;j++){
      int v0=(int)(short)(wvals[j]&0xffff), v1=wvals[j]>>16;
      float f0 = ((float)v0-mu[2*j])*kk[2*j]+bb[2*j];
      float f1 = ((float)v1-mu[2*j+1])*kk[2*j+1]+bb[2*j+1];
      wv |= (f0>0.f?1u:0u)<<(2*j);
      wv |= (f1>0.f?1u:0u)<<(2*j+1);
    }
    A3[img][oh][ow+1] = wv;
    if (ow==0)  A3[img][oh][0]  = 0;
    if (ow==10) A3[img][oh][12] = 0;
  }
  __syncthreads();
  int acc[24], sq[24];
  #pragma unroll
  for (int i=0;i<24;i++){ acc[i]=0; sq[i]=0; }
  int grp = t & 1;                       // == (u%30)&1 for all iterations (30 even, 256 even)
  // conv3: 16 img x 15 px x 2 groups = 480 units
  for (int u=t; u<16*30; u+=256) {
    int img = u/30, rem = u%30;
    int px = rem>>1;
    int oh = px/5, ow = px%5;
    int P[24], T = 0;
    #pragma unroll
    for (int i=0;i<24;i++) P[i]=0;
    for (int kh=0; kh<5; kh++) {
      int row = 2*oh-1+kh;
      if ((unsigned)row >= 7u) continue;
      const u32* pr = &A3[img][row][2*ow];
      u64 a0=pr[0],a1=pr[1],a2=pr[2],a3=pr[3],a4=pr[4];
      u64 x0 = a0 | (a1<<24) | (a2<<48);
      u64 x1 = (a2>>16) | (a3<<8) | (a4<<32);
      T += __popcll(x0) + __popcll(x1);
      const u64* wr = W3 + kh*4;
      #pragma unroll
      for (int j=0;j<24;j++){
        const u64* qq = wr + (grp*24+j)*20;
        P[j] += __popcll(x0&qq[0]) + __popcll(x1&qq[1]);
      }
    }
    short* o = S3 + ((size_t)(n0+img)*15 + px)*48 + grp*24;
    #pragma unroll
    for (int j=0;j<24;j++){ int sv = 2*P[j]-T; o[j]=(short)sv; acc[j]+=sv; sq[j]+=sv*sv; }
  }
  int v[48];
  #pragma unroll
  for (int c=0;c<24;c++){ v[c]=acc[c]; v[24+c]=sq[c]; }
  block_stats<48,2,24>(v, tot+72, rl);
}

// ---------------- L4 fused: thresh3 + conv4 + stats4 ----------------
// 256 blocks x 32 images. A4 (3x7 u64/img) in LDS. conv: 32 img x 2 ow x 4 grp = 256 units exact.
__global__ __launch_bounds__(256) void layer4_k(const short* __restrict__ S3, u64* tot,
    const float* __restrict__ g, const float* __restrict__ be,
    const u64* __restrict__ W4, short* __restrict__ S4) {
  __shared__ float mu[48], kk[48], bb[48];
  bn_params<48>(tot+72, g, be, 122880.0, mu, kk, bb);
  __shared__ u64 A4[32][3][7];
  __shared__ int rl[4*48*4];
  int t = threadIdx.x;
  int n0 = blockIdx.x*32;
  // thresh3: 32 x 15 px
  for (int u=t; u<32*15; u+=256) {
    int img = u/15, px = u%15;
    int oh = px/5, ow = px%5;
    const int4* s4 = (const int4*)(S3 + ((size_t)(n0+img)*15 + px)*48);
    u64 wv = 0;
    #pragma unroll
    for (int q4=0;q4<6;q4++){
      int4 w4v = s4[q4];
      int wa[4]={w4v.x,w4v.y,w4v.z,w4v.w};
      #pragma unroll
      for (int j=0;j<4;j++){
        int c = q4*8 + j*2;
        int v0=(int)(short)(wa[j]&0xffff), v1=wa[j]>>16;
        float f0=((float)v0-mu[c])*kk[c]+bb[c];
        float f1=((float)v1-mu[c+1])*kk[c+1]+bb[c+1];
        wv |= (u64)(f0>0.f?1u:0u)<<c;
        wv |= (u64)(f1>0.f?1u:0u)<<(c+1);
      }
    }
    A4[img][oh][ow+1] = wv;
    if (ow==0) A4[img][oh][0] = 0;
    if (ow==4) A4[img][oh][6] = 0;
  }
  __syncthreads();
  // conv4: one unit per thread
  int img = t>>3, unit = t&7, ow = unit>>2, grp = unit&3;   // grp == lane&3
  int P[24], T = 0;
  #pragma unroll
  for (int i=0;i<24;i++) P[i]=0;
  for (int kh=0; kh<5; kh++) {
    int row = kh-1;                       // oh = 0 only
    if ((unsigned)row >= 3u) continue;
    const u64* pr = &A4[img][row][2*ow];
    u64 a0=pr[0],a1=pr[1],a2=pr[2],a3=pr[3],a4=pr[4];
    u64 x0 = a0 | (a1<<48);
    u64 x1 = (a1>>16) | (a2<<32);
    u64 x2 = (a2>>32) | (a3<<16);
    u64 x3 = a4;
    T += __popcll(x0)+__popcll(x1)+__popcll(x2)+__popcll(x3);
    const u64* wr = W4 + kh*8;
    #pragma unroll
    for (int j=0;j<24;j++){
      const u64* qq = wr + (grp*24+j)*40;
      P[j] += __popcll(x0&qq[0])+__popcll(x1&qq[1])+__popcll(x2&qq[2])+__popcll(x3&qq[3]);
    }
  }
  short* o = S4 + ((size_t)(n0+img)*2 + ow)*96 + grp*24;
  int v[48];
  #pragma unroll
  for (int j=0;j<24;j++){ int sv = 2*P[j]-T; o[j]=(short)sv; v[j]=sv; v[24+j]=sv*sv; }
  block_stats<48,4,24>(v, tot+168, rl);
}

// ---------------- L5 fused: thresh4 + linear ----------------
// 2048 blocks x 4 images. aL built per image via wave ballot (bit k=c*2+w).
// 4 waves per block; 12 (img,word) chunks -> stride 4.
__global__ __launch_bounds__(256) void layer5_k(const short* __restrict__ S4, u64* tot,
    const float* __restrict__ g, const float* __restrict__ be,
    const u64* __restrict__ WL, const float* __restrict__ bl, float* __restrict__ out) {
  __shared__ float mu[96], kk[96], bb[96];
  bn_params<96>(tot+168, g, be, 16384.0, mu, kk, bb);
  __shared__ u64 AL[4][3];
  __shared__ int ALT[4];
  int t = threadIdx.x, lane = t & 63, wid = t >> 6;
  int n0 = blockIdx.x*4;
  // 12 (img,word) ballot chunks over 4 waves (3 each)
  for (int ch = wid; ch < 12; ch += 4) {
    int img = ch/3, word = ch%3;
    int k = word*64 + lane;
    int c = k>>1, wp = k&1;               // reshape(96,1,2)->192: k = c*2 + w
    int sv = S4[((size_t)(n0+img)*2 + wp)*96 + c];
    float f = ((float)sv-mu[c])*kk[c]+bb[c];
    u64 m = __ballot(f > 0.f);
    if (lane == 0) AL[img][word] = m;
  }
  __syncthreads();
  if (t < 4) ALT[t] = __popcll(AL[t][0]) + __popcll(AL[t][1]) + __popcll(AL[t][2]);
  __syncthreads();
  // linear: 4 x 360 outputs;  S = 2*popc(a & w+) - popc(a)
  for (int u=t; u<4*360; u+=256) {
    int img = u/360, o = u%360;
    const u64* w = WL + (size_t)o*6;
    u64 a0=AL[img][0], a1=AL[img][1], a2=AL[img][2];
    int S = 2*(__popcll(a0&w[0]) + __popcll(a1&w[1]) + __popcll(a2&w[2])) - ALT[img];
    out[(size_t)(n0+img)*360 + o] = (float)S + bl[o];
  }
}

extern "C" void kernel_launch(void* const* d_in, const int* in_sizes, int n_in,
                              void* d_out, int out_size, void* d_ws, size_t ws_size,
                              hipStream_t stream) {
  const float* x  = (const float*)d_in[0];
  const float* w1 = (const float*)d_in[1];
  const float* g1 = (const float*)d_in[3];
  const float* be1= (const float*)d_in[4];
  const float* w2 = (const float*)d_in[5];
  const float* g2 = (const float*)d_in[7];
  const float* be2= (const float*)d_in[8];
  const float* w3 = (const float*)d_in[9];
  const float* g3 = (const float*)d_in[11];
  const float* be3= (const float*)d_in[12];
  const float* w4 = (const float*)d_in[13];
  const float* g4 = (const float*)d_in[15];
  const float* be4= (const float*)d_in[16];
  const float* wl = (const float*)d_in[17];
  const float* bl = (const float*)d_in[18];

  char* ws = (char*)d_ws;
  u64* tot = (u64*)(ws + O_TOT);
  u64* W1  = (u64*)(ws + O_W1);
  u64* W2  = (u64*)(ws + O_W2);
  u64* W3  = (u64*)(ws + O_W3);
  u64* W4  = (u64*)(ws + O_W4);
  u64* WL  = (u64*)(ws + O_WL);
  u32*   S1 = (u32*)(ws + O_SA);
  short* S2 = (short*)(ws + O_SB);
  short* S3 = (short*)(ws + O_SA);   // S1 dead after layer2
  short* S4 = (short*)(ws + O_SB);   // S2 dead after layer3

  pack_w_k<<<6,256,0,stream>>>(w1,w2,w3,w4,wl, W1,W2,W3,W4,WL, tot);
  layer1_k<<<2048,256,0,stream>>>(x, W1, S1, tot);
  layer2_k<<<1024,256,0,stream>>>(S1, tot, g1, be1, W2, S2);
  layer3_k<<<512,256,0,stream>>>(S2, tot, g2, be2, W3, S3);
  layer4_k<<<256,256,0,stream>>>(S3, tot, g3, be3, W4, S4);
  layer5_k<<<2048,256,0,stream>>>(S4, tot, g4, be4, WL, bl, (float*)d_out);
}